// Round 13
// baseline (161.582 us; speedup 1.0000x reference)
//
#include <hip/hip_runtime.h>
#include <cstddef>
#include <cstdint>

// ---------------------------------------------------------------------------
// MultiGroupDMoN forward.
// R13: k_rows rewritten on MFMA (mfma_f32_16x16x32_f16):
//   logits = Ftile(32x256) @ W(256x16)  -> 16 MFMA/tile (2 M-tiles x 8 K-steps)
//   P     += S^T(16x32) @ Ftile(32x256) -> 16 MFMA/tile (16 N-chunks)
//   F staged row-major (A frags) + transposed (B frags of P).
// k_edge: reverted to R11 exact config (best measured 71us; gather rate is
//   structurally capped ~0.27/cy/CU regardless of occupancy).
// ws layout (floats):
//   [OFF_E .. +3*18*EGRID)   edge partials [g][slot][block]
//   [OFF_R .. +4112)         reduced P[4096]+cs[16]   (memset 0)
//   [OFF_G .. +64)           G54 reduced accumulators
//   [OFF_F8.. +4n)           fp8 S (n rows x 16 bytes, as u32)
//   [OFF_P .. +grid1*4112)   per-block k_rows partials
// ---------------------------------------------------------------------------

#define G1_MAX   1024
#define EGRID    2048
#define NSEG     16
#define OFF_E    0
#define SZ_E     (3 * 18 * EGRID)
#define OFF_R    (OFF_E + SZ_E)
#define OFF_G    (OFF_R + 4112)
#define OFF_F8   (OFF_G + 64)

#define TROWS    32
#define RSTR     264    // u16 stride of rows_u16 / Wt_u16 (264*2B = 16B-mult)
#define TSTR     40     // u16 stride of rowsT_u16 / St_u16 (80B = 16B-mult)

#define BLK0     1024   // k_edge blocks: adj
#define BLK12    512    // k_edge blocks: g1, g2

typedef int      iv4  __attribute__((ext_vector_type(4)));
typedef float    fv4  __attribute__((ext_vector_type(4)));
typedef unsigned uv4  __attribute__((ext_vector_type(4)));
typedef _Float16 hh;
typedef hh       h2   __attribute__((ext_vector_type(2)));
typedef hh       h8   __attribute__((ext_vector_type(8)));
typedef float    f32x4 __attribute__((ext_vector_type(4)));

#if __has_builtin(__builtin_amdgcn_cvt_pk_f32_fp8)
#define HW_FP8 1
#endif

__device__ __forceinline__ h2 bch2(unsigned u) { return __builtin_bit_cast(h2, u); }

__device__ __forceinline__ unsigned pk16u(float x, float y)
{
#if __has_builtin(__builtin_amdgcn_cvt_pkrtz)
    return __builtin_bit_cast(unsigned, __builtin_amdgcn_cvt_pkrtz(x, y));
#else
    h2 r; r[0] = (hh)x; r[1] = (hh)y; return __builtin_bit_cast(unsigned, r);
#endif
}
__device__ __forceinline__ unsigned short h16(float x)
{
    return (unsigned short)(pk16u(x, 0.f) & 0xFFFFu);
}

// ---- software e4m3fn encode ----
__device__ __forceinline__ unsigned f32_to_e4m3(float f)
{
    unsigned bits = __float_as_uint(f);
    unsigned s = bits >> 31;
    int e32 = (int)((bits >> 23) & 255);
    unsigned m23 = bits & 0x7FFFFF;
    int e = e32 - 120;
    unsigned out;
    if (e32 == 0) out = 0;
    else if (e <= 0) {
        float av = fabsf(f);
        int q = (int)(av * 512.0f + 0.5f);
        out = (unsigned)q;
    } else if (e > 15) out = (15u << 3) | 6u;
    else {
        unsigned m3 = (m23 + 0x80000u) >> 20;
        if (m3 == 8u) { m3 = 0u; ++e; if (e > 15) { e = 15; m3 = 6u; } }
        out = ((unsigned)e << 3) | m3;
    }
    return out | (s << 7);
}

// ---- decode 16 fp8 bytes to floats ----
__device__ __forceinline__ void decode16(uint4 r, float* o, const float* lut)
{
#ifdef HW_FP8
    #pragma unroll
    for (int j = 0; j < 4; ++j) {
        unsigned u = (&r.x)[j];
        auto lo = __builtin_amdgcn_cvt_pk_f32_fp8(u, false);
        auto hi = __builtin_amdgcn_cvt_pk_f32_fp8(u, true);
        o[4*j]   = lo[0]; o[4*j+1] = lo[1];
        o[4*j+2] = hi[0]; o[4*j+3] = hi[1];
    }
#else
    #pragma unroll
    for (int j = 0; j < 4; ++j) {
        unsigned u = (&r.x)[j];
        #pragma unroll
        for (int q = 0; q < 4; ++q)
            o[4*j+q] = lut[(u >> (8*q)) & 255];
    }
#endif
}

__global__ void __launch_bounds__(256)
k_rows(const float* __restrict__ F, const float* __restrict__ W,
       const float* __restrict__ b, float* __restrict__ S_out,
       unsigned* __restrict__ S_f8, float* __restrict__ ws_P, int n, int n_tiles)
{
    __shared__ unsigned short Wt_u16[16][RSTR];     // Wt[n][k] fp16
    __shared__ unsigned short rows_u16[TROWS][RSTR];// F row-major fp16
    __shared__ unsigned short rowsT_u16[256][TSTR]; // F transposed [d][r]
    __shared__ unsigned short St_u16[16][TSTR];     // S^T [k-cluster][row]
    __shared__ float Sred[2][16][17];               // logits cross-wave partials
    __shared__ float cs_red[256];

    const int t = threadIdx.x;
    const int w = t >> 6;        // wave 0..3
    const int l = t & 63;        // lane
    const int l15 = l & 15;
    const int lg  = l >> 4;      // 0..3

    // stage Wt[n][k] = fp16(W[k][n])
    for (int idx = t; idx < 4096; idx += 256) {
        int k = idx >> 4, nn = idx & 15;
        Wt_u16[nn][k] = h16(W[idx]);
    }
    const float bk = b[l15];

    f32x4 pacc[4];
    #pragma unroll
    for (int j = 0; j < 4; ++j) pacc[j] = (f32x4){0.f, 0.f, 0.f, 0.f};
    float cs_acc = 0.f;

    // register prefetch: 8 float4 = this thread's slice of a tile
    float4 stg[8];
    auto load_tile = [&](int tl) {
        const float4* F4 = (const float4*)(F + (size_t)tl * TROWS * 256);
        #pragma unroll
        for (int q = 0; q < 8; ++q) {
            int r = (t >> 6) + 4 * q;
            float4 z = {0.f, 0.f, 0.f, 0.f};
            stg[q] = (tl * TROWS + r < n) ? F4[t + (q << 8)] : z;
        }
    };
    if (blockIdx.x < (unsigned)n_tiles) load_tile(blockIdx.x);
    __syncthreads();   // Wt ready

    for (int tile = blockIdx.x; tile < n_tiles; tile += gridDim.x) {
        // ---- stage both layouts from registers ----
        const int c4 = t & 63;
        #pragma unroll
        for (int q = 0; q < 8; ++q) {
            int r = (t >> 6) + 4 * q;
            unsigned u0 = pk16u(stg[q].x, stg[q].y);
            unsigned u1 = pk16u(stg[q].z, stg[q].w);
            *(uint2*)&rows_u16[r][c4 << 2] = make_uint2(u0, u1);
            rowsT_u16[(c4 << 2) + 0][r] = (unsigned short)(u0 & 0xFFFFu);
            rowsT_u16[(c4 << 2) + 1][r] = (unsigned short)(u0 >> 16);
            rowsT_u16[(c4 << 2) + 2][r] = (unsigned short)(u1 & 0xFFFFu);
            rowsT_u16[(c4 << 2) + 3][r] = (unsigned short)(u1 >> 16);
        }
        __syncthreads();

        // prefetch next tile (overlaps MFMA phases)
        {
            int nt2 = tile + gridDim.x;
            if (nt2 < n_tiles) load_tile(nt2);
        }

        // ---- logits MFMA: wave w -> M-tile (w&1), K-steps (w>>1)*4.. ----
        const int mt  = w & 1;
        const int ks0 = (w >> 1) * 4;
        f32x4 c0 = (f32x4){0.f, 0.f, 0.f, 0.f};
        #pragma unroll
        for (int s = 0; s < 4; ++s) {
            int k0 = (ks0 + s) << 5;            // *32
            uv4 av = *(const uv4*)&rows_u16[(mt << 4) + l15][k0 + (lg << 3)];
            uv4 bv = *(const uv4*)&Wt_u16[l15][k0 + (lg << 3)];
            c0 = __builtin_amdgcn_mfma_f32_16x16x32_f16(
                     __builtin_bit_cast(h8, av), __builtin_bit_cast(h8, bv),
                     c0, 0, 0, 0);
        }
        if (w >= 2) {
            #pragma unroll
            for (int p = 0; p < 4; ++p)
                Sred[mt][(lg << 2) + p][l15] = c0[p];
        }
        __syncthreads();

        if (w < 2) {
            // merge K-halves + bias, softmax over 16 cols (lanes) per row
            float lv[4];
            #pragma unroll
            for (int p = 0; p < 4; ++p)
                lv[p] = c0[p] + Sred[mt][(lg << 2) + p][l15] + bk;
            float mx[4], sm[4];
            #pragma unroll
            for (int p = 0; p < 4; ++p) mx[p] = lv[p];
            #pragma unroll
            for (int o = 8; o; o >>= 1)
                #pragma unroll
                for (int p = 0; p < 4; ++p)
                    mx[p] = fmaxf(mx[p], __shfl_xor(mx[p], o));
            #pragma unroll
            for (int p = 0; p < 4; ++p) { lv[p] = __expf(lv[p] - mx[p]); sm[p] = lv[p]; }
            #pragma unroll
            for (int o = 8; o; o >>= 1)
                #pragma unroll
                for (int p = 0; p < 4; ++p)
                    sm[p] += __shfl_xor(sm[p], o);
            float sv[4];
            int rbase = tile * TROWS + (mt << 4) + (lg << 2);
            #pragma unroll
            for (int p = 0; p < 4; ++p) {
                sv[p] = lv[p] / sm[p];
                if (rbase + p < n) cs_acc += sv[p];
            }
            // write S^T fragment: St[k=l15][rows (mt*16 + lg*4)..+4]
            unsigned su0 = pk16u(sv[0], sv[1]);
            unsigned su1 = pk16u(sv[2], sv[3]);
            *(uint2*)&St_u16[l15][(mt << 4) + (lg << 2)] = make_uint2(su0, su1);
        }
        __syncthreads();   // St ready

        // ---- S_out (fp32) + fp8 pack, coalesced from St ----
        if (t < 128) {
            int r = t >> 2, c = t & 3;
            int row = tile * TROWS + r;
            if (row < n) {
                float v0 = (float)__builtin_bit_cast(hh, St_u16[4*c + 0][r]);
                float v1 = (float)__builtin_bit_cast(hh, St_u16[4*c + 1][r]);
                float v2 = (float)__builtin_bit_cast(hh, St_u16[4*c + 2][r]);
                float v3 = (float)__builtin_bit_cast(hh, St_u16[4*c + 3][r]);
                *(float4*)&S_out[((size_t)row << 4) + 4*c] = make_float4(v0, v1, v2, v3);
                unsigned u = f32_to_e4m3(v0) | (f32_to_e4m3(v1) << 8)
                           | (f32_to_e4m3(v2) << 16) | (f32_to_e4m3(v3) << 24);
                S_f8[((size_t)row << 2) + c] = u;
            }
        }

        // ---- P MFMA: P(16 x 256) += S^T(16x32) @ F(32x256) ----
        {
            uv4 sa = *(const uv4*)&St_u16[l15][lg << 3];
            h8  ah = __builtin_bit_cast(h8, sa);
            #pragma unroll
            for (int j = 0; j < 4; ++j) {
                int nc = (w << 2) + j;
                uv4 bv = *(const uv4*)&rowsT_u16[(nc << 4) + l15][lg << 3];
                pacc[j] = __builtin_amdgcn_mfma_f32_16x16x32_f16(
                              ah, __builtin_bit_cast(h8, bv), pacc[j], 0, 0, 0);
            }
        }
        __syncthreads();   // before next tile overwrites LDS
    }

    // ---- flush P partials: lane reg p of pacc[j] -> P[4*lg+p][w*64 + j*16 + l15]
    {
        float* dst = ws_P + (size_t)blockIdx.x * 4112;
        #pragma unroll
        for (int j = 0; j < 4; ++j)
            #pragma unroll
            for (int p = 0; p < 4; ++p)
                dst[((lg << 2) + p) * 256 + (w << 6) + (j << 4) + l15] = pacc[j][p];
    }
    cs_red[t] = cs_acc;
    __syncthreads();
    if (t < 16) {
        float ssum = 0.f;
        #pragma unroll
        for (int i = 0; i < 16; ++i) ssum += cs_red[t + (i << 4)];
        ws_P[(size_t)blockIdx.x * 4112 + 4096 + t] = ssum;
    }
}

__global__ void __launch_bounds__(256)
k_reduce(const float* __restrict__ ws_P, float* __restrict__ ws_red, int nb)
{
    const int seg  = blockIdx.x & (NSEG - 1);
    const int jblk = blockIdx.x / NSEG;
    const int idx  = jblk * 256 + threadIdx.x;
    if (idx >= 4112) return;
    const int chunk = (nb + NSEG - 1) / NSEG;
    const int b0 = seg * chunk;
    const int b1 = min(nb, b0 + chunk);
    float s = 0.f;
    for (int bb = b0; bb < b1; ++bb)
        s += ws_P[(size_t)bb * 4112 + idx];
    atomicAdd(&ws_red[idx], s);
}

// fused edge kernel (R11 config): 4 edges/iter, 2048 blocks, high occupancy
__global__ void __launch_bounds__(256, 4)
k_edge(const int* __restrict__ src0, const int* __restrict__ dst0,
       const float* __restrict__ val0, int n0,
       const int* __restrict__ src1, const int* __restrict__ dst1,
       const float* __restrict__ val1, int n1,
       const int* __restrict__ src2, const int* __restrict__ dst2,
       const float* __restrict__ val2, int n2,
       const uint4* __restrict__ S8, float* __restrict__ ws_e,
       int b0, int b1)
{
#ifndef HW_FP8
    __shared__ float lut[256];
    if (threadIdx.x < 256) {
        int i = threadIdx.x;
        int e_ = (i >> 3) & 15, m_ = i & 7, s_ = i >> 7;
        float v = e_ ? ldexpf((float)(8 + m_), e_ - 10) : ldexpf((float)m_, -9);
        lut[i] = s_ ? -v : v;
    }
    __syncthreads();
    const float* lutp = lut;
#else
    const float* lutp = nullptr;
#endif

    int g, bb, nblk, nE;
    const int* src; const int* dst; const float* val;
    if ((int)blockIdx.x < b0)      { g = 0; bb = blockIdx.x;      nblk = b0;             src = src0; dst = dst0; val = val0; nE = n0; }
    else if ((int)blockIdx.x < b1) { g = 1; bb = blockIdx.x - b0; nblk = b1 - b0;        src = src1; dst = dst1; val = val1; nE = n1; }
    else                           { g = 2; bb = blockIdx.x - b1; nblk = gridDim.x - b1; src = src2; dst = dst2; val = val2; nE = n2; }

    float m_acc = 0.f, tr_acc = 0.f;
    float gds[16];
    #pragma unroll
    for (int k = 0; k < 16; ++k) gds[k] = 0.f;

    const int nv = nE >> 2;                    // 4 edges per thread-iter
    const iv4* s4 = (const iv4*)src;
    const iv4* d4 = (const iv4*)dst;
    const fv4* v4 = (const fv4*)val;
    const int stride = nblk * 256;

    for (int i = bb * 256 + threadIdx.x; i < nv; i += stride) {
        iv4 sa = __builtin_nontemporal_load(&s4[i]);
        iv4 da = __builtin_nontemporal_load(&d4[i]);
        fv4 va = __builtin_nontemporal_load(&v4[i]);
        uint4 rs[4], rd[4];
        #pragma unroll
        for (int e = 0; e < 4; ++e) {
            rs[e] = S8[sa[e]];
            rd[e] = S8[da[e]];
        }
        #pragma unroll
        for (int e = 0; e < 4; ++e) {
            float sv[16], dv[16];
            decode16(rs[e], sv, lutp);
            decode16(rd[e], dv, lutp);
            float v = va[e];
            float dot = 0.f;
            #pragma unroll
            for (int k = 0; k < 16; ++k) dot = fmaf(sv[k], dv[k], dot);
            m_acc += v;
            tr_acc = fmaf(v, dot, tr_acc);
            #pragma unroll
            for (int k = 0; k < 16; ++k) gds[k] = fmaf(v, dv[k], gds[k]);
        }
    }

    // tail (nE % 4): block 0 of this graph
    if (bb == 0) {
        int e = (nv << 2) + threadIdx.x;
        if (e < nE) {
            float sv[16], dv[16];
            decode16(S8[src[e]], sv, lutp);
            decode16(S8[dst[e]], dv, lutp);
            float v = val[e];
            float dot = 0.f;
            #pragma unroll
            for (int k = 0; k < 16; ++k) dot = fmaf(sv[k], dv[k], dot);
            m_acc += v;
            tr_acc = fmaf(v, dot, tr_acc);
            #pragma unroll
            for (int k = 0; k < 16; ++k) gds[k] = fmaf(v, dv[k], gds[k]);
        }
    }

    #pragma unroll
    for (int o = 32; o; o >>= 1) {
        m_acc  += __shfl_xor(m_acc, o);
        tr_acc += __shfl_xor(tr_acc, o);
        #pragma unroll
        for (int k = 0; k < 16; ++k) gds[k] += __shfl_xor(gds[k], o);
    }
    __shared__ float wred[4][18];
    const int wid = threadIdx.x >> 6, lane = threadIdx.x & 63;
    if (lane == 0) {
        wred[wid][0] = m_acc; wred[wid][1] = tr_acc;
        #pragma unroll
        for (int k = 0; k < 16; ++k) wred[wid][2 + k] = gds[k];
    }
    __syncthreads();
    if (threadIdx.x < 18) {
        float s = wred[0][threadIdx.x] + wred[1][threadIdx.x]
                + wred[2][threadIdx.x] + wred[3][threadIdx.x];
        ws_e[(size_t)g * 18 * EGRID + (size_t)threadIdx.x * EGRID + bb] = s;
    }
}

__global__ void __launch_bounds__(256)
k_ereduce(const float* __restrict__ ws_e, float* __restrict__ G54,
          int g0, int g1, int g2)
{
    const int p = blockIdx.x;            // 0..53
    const int g = p / 18, slot = p % 18;
    int grids[3] = {g0, g1, g2};
    const int gb = grids[g];
    const float* base = ws_e + (size_t)g * 18 * EGRID + (size_t)slot * EGRID;

    const int t = threadIdx.x;
    float s = 0.f;
    for (int bb = t; bb < gb; bb += 256) s += base[bb];
    #pragma unroll
    for (int o = 32; o; o >>= 1) s += __shfl_xor(s, o);

    __shared__ float wr[4];
    if ((t & 63) == 0) wr[t >> 6] = s;
    __syncthreads();
    if (t == 0) G54[p] = wr[0] + wr[1] + wr[2] + wr[3];
}

__global__ void __launch_bounds__(256)
k_final(const float* __restrict__ ws_red, const float* __restrict__ G54,
        const void* __restrict__ lamda_ptr, float* __restrict__ out, int n)
{
    __shared__ float G[54];
    const int t = threadIdx.x;
    if (t < 54) G[t] = G54[t];
    __syncthreads();

    const float* P  = ws_red;
    const float* cs = ws_red + 4096;

    const float scale = 1.0507009873554805f;
    const float alpha = 1.6732632423543772f;
    for (int idx = t; idx < 4096; idx += 256) {
        int k = idx >> 8;
        float x = P[idx] / cs[k];
        float y = x > 0.f ? scale * x : scale * alpha * (expf(x) - 1.f);
        out[idx] = y;
    }

    if (t == 0) {
        int   li = *(const int*)lamda_ptr;
        float lf = *(const float*)lamda_ptr;
        float lamda = (li > -100000 && li < 100000) ? (float)li : lf;

        float m = G[0], trA = G[1];
        float ds2 = 0.f;
        for (int k = 0; k < 16; ++k) ds2 += G[2 + k] * G[2 + k];
        float spectral = -(trA - ds2 / (2.f * m)) / (2.f * m);

        float Q[2], gm[2];
        for (int g = 0; g < 2; ++g) {
            const float* Gg = G + 18 * (g + 1);
            float mg = Gg[0], trg = Gg[1];
            float gds2 = 0.f;
            for (int k = 0; k < 16; ++k) gds2 += Gg[2 + k] * Gg[2 + k];
            float safe = mg > 0.f ? mg : 1.f;
            float q = (trg - gds2 / (2.f * safe)) / (2.f * m);
            Q[g]  = mg > 0.f ? q : 0.f;
            gm[g] = mg;
        }
        float Qmin = fminf(Q[0], Q[1]);
        float gmean = 0.5f * (gm[0] + gm[1]);
        float fairness = (m / (gmean + 1e-8f)) * (-Qmin);

        float csn = 0.f;
        for (int k = 0; k < 16; ++k) csn += cs[k] * cs[k];
        float collapse = (sqrtf(csn) / (float)n) * 4.f - 1.f;

        out[4096 + (size_t)n * 16] = spectral + lamda * fairness + 0.1f * collapse;
    }
}

extern "C" void kernel_launch(void* const* d_in, const int* in_sizes, int n_in,
                              void* d_out, int out_size, void* d_ws, size_t ws_size,
                              hipStream_t stream)
{
    const float* F       = (const float*)d_in[0];
    const float* W       = (const float*)d_in[1];
    const float* b       = (const float*)d_in[2];
    const int*   adj_src = (const int*)d_in[3];
    const int*   adj_dst = (const int*)d_in[4];
    const float* adj_val = (const float*)d_in[5];
    const int*   g1_src  = (const int*)d_in[6];
    const int*   g1_dst  = (const int*)d_in[7];
    const float* g1_val  = (const float*)d_in[8];
    const int*   g2_src  = (const int*)d_in[9];
    const int*   g2_dst  = (const int*)d_in[10];
    const float* g2_val  = (const float*)d_in[11];
    const void*  lamda_p = d_in[12];

    const int n  = in_sizes[0] / 256;
    const int nE = in_sizes[3];
    const int n1 = in_sizes[6];
    const int n2 = in_sizes[9];

    float* out   = (float*)d_out;
    float* S_out = out + 4096;

    float* ws   = (float*)d_ws;
    float* ws_e = ws + OFF_E;
    float* ws_r = ws + OFF_R;
    float* ws_g = ws + OFF_G;
    unsigned* S8 = (unsigned*)(ws + OFF_F8);
    const size_t off_p = (size_t)OFF_F8 + (size_t)n * 4;
    float* ws_P = ws + off_p;

    const int n_tiles = (n + TROWS - 1) / TROWS;
    long avail = ((long)(ws_size / 4) - (long)off_p) / 4112;
    int grid1 = n_tiles < G1_MAX ? n_tiles : G1_MAX;
    if (avail < grid1) grid1 = (int)avail;
    if (grid1 < 1) grid1 = 1;

    (void)hipMemsetAsync(ws_r, 0, 4112 * sizeof(float), stream);

    k_rows<<<grid1, 256, 0, stream>>>(F, W, b, S_out, S8, ws_P, n, n_tiles);
    k_reduce<<<17 * NSEG, 256, 0, stream>>>(ws_P, ws_r, grid1);

    const int b0 = BLK0, b1g = BLK12, b2g = BLK12;
    k_edge<<<b0 + b1g + b2g, 256, 0, stream>>>(
        adj_src, adj_dst, adj_val, nE,
        g1_src, g1_dst, g1_val, n1,
        g2_src, g2_dst, g2_val, n2,
        (const uint4*)S8, ws_e, b0, b0 + b1g);

    k_ereduce<<<54, 256, 0, stream>>>(ws_e, ws_g, b0, b1g, b2g);
    k_final<<<1, 256, 0, stream>>>(ws_r, ws_g, lamda_p, out, n);
}

// Round 14
// 143.715 us; speedup vs baseline: 1.1243x; 1.1243x over previous
//
#include <hip/hip_runtime.h>
#include <cstddef>
#include <cstdint>

// ---------------------------------------------------------------------------
// MultiGroupDMoN forward.
// R14 = R11 structure + MFMA for logits ONLY (layout proven in R13):
//   logits: Ftile(32x256)@W(256x16) via mfma_f32_16x16x32_f16 (A=row-major F,
//           B=Wt[n][k] — both already staged; K split across wave pairs)
//   P:      R11 pk_fma from row-major LDS (NO transposed staging — that's
//           what sank R13)
// k_edge: R11 config (71us structural floor: ~0.28 lane-gathers/cy/CU across
//   3 occupancy configs; 2 gathers/edge algebraically irreducible).
// ws layout (floats):
//   [OFF_E .. +3*18*EGRID)   edge partials [g][slot][block]
//   [OFF_R .. +4112)         reduced P[4096]+cs[16]   (memset 0)
//   [OFF_G .. +64)           G54 reduced accumulators
//   [OFF_F8.. +4n)           fp8 S (n rows x 16 bytes, as u32)
//   [OFF_P .. +grid1*4112)   per-block k_rows partials
// ---------------------------------------------------------------------------

#define G1_MAX   1024
#define EGRID    2048
#define NSEG     16
#define OFF_E    0
#define SZ_E     (3 * 18 * EGRID)
#define OFF_R    (OFF_E + SZ_E)
#define OFF_G    (OFF_R + 4112)
#define OFF_F8   (OFF_G + 64)

#define TROWS    32
#define RSTR     264    // u16 stride: 264*2B=528B, odd dw count -> bank spread

#define BLK0     1024   // k_edge blocks: adj
#define BLK12    512    // k_edge blocks: g1, g2

typedef int      iv4  __attribute__((ext_vector_type(4)));
typedef float    fv4  __attribute__((ext_vector_type(4)));
typedef unsigned uv4  __attribute__((ext_vector_type(4)));
typedef _Float16 hh;
typedef hh       h2   __attribute__((ext_vector_type(2)));
typedef hh       h8   __attribute__((ext_vector_type(8)));
typedef float    f32x4 __attribute__((ext_vector_type(4)));

#if __has_builtin(__builtin_amdgcn_cvt_pk_f32_fp8)
#define HW_FP8 1
#endif

__device__ __forceinline__ h2 bch2(unsigned u) { return __builtin_bit_cast(h2, u); }

__device__ __forceinline__ unsigned pk16u(float x, float y)
{
#if __has_builtin(__builtin_amdgcn_cvt_pkrtz)
    return __builtin_bit_cast(unsigned, __builtin_amdgcn_cvt_pkrtz(x, y));
#else
    h2 r; r[0] = (hh)x; r[1] = (hh)y; return __builtin_bit_cast(unsigned, r);
#endif
}
__device__ __forceinline__ h2 pk16(float x, float y)
{
    return __builtin_bit_cast(h2, pk16u(x, y));
}
__device__ __forceinline__ unsigned short h16(float x)
{
    return (unsigned short)(pk16u(x, 0.f) & 0xFFFFu);
}

// ---- software e4m3fn encode ----
__device__ __forceinline__ unsigned f32_to_e4m3(float f)
{
    unsigned bits = __float_as_uint(f);
    unsigned s = bits >> 31;
    int e32 = (int)((bits >> 23) & 255);
    unsigned m23 = bits & 0x7FFFFF;
    int e = e32 - 120;
    unsigned out;
    if (e32 == 0) out = 0;
    else if (e <= 0) {
        float av = fabsf(f);
        int q = (int)(av * 512.0f + 0.5f);
        out = (unsigned)q;
    } else if (e > 15) out = (15u << 3) | 6u;
    else {
        unsigned m3 = (m23 + 0x80000u) >> 20;
        if (m3 == 8u) { m3 = 0u; ++e; if (e > 15) { e = 15; m3 = 6u; } }
        out = ((unsigned)e << 3) | m3;
    }
    return out | (s << 7);
}

// ---- decode 16 fp8 bytes to floats ----
__device__ __forceinline__ void decode16(uint4 r, float* o, const float* lut)
{
#ifdef HW_FP8
    #pragma unroll
    for (int j = 0; j < 4; ++j) {
        unsigned u = (&r.x)[j];
        auto lo = __builtin_amdgcn_cvt_pk_f32_fp8(u, false);
        auto hi = __builtin_amdgcn_cvt_pk_f32_fp8(u, true);
        o[4*j]   = lo[0]; o[4*j+1] = lo[1];
        o[4*j+2] = hi[0]; o[4*j+3] = hi[1];
    }
#else
    #pragma unroll
    for (int j = 0; j < 4; ++j) {
        unsigned u = (&r.x)[j];
        #pragma unroll
        for (int q = 0; q < 4; ++q)
            o[4*j+q] = lut[(u >> (8*q)) & 255];
    }
#endif
}

__global__ void __launch_bounds__(256)
k_rows(const float* __restrict__ F, const float* __restrict__ W,
       const float* __restrict__ b, float* __restrict__ S_out,
       unsigned* __restrict__ S_f8, float* __restrict__ ws_P, int n, int n_tiles)
{
    __shared__ unsigned short Wt_u16[16][RSTR];      // Wt[n][k] fp16
    __shared__ unsigned short rows_u16[TROWS][RSTR]; // F row-major fp16
    __shared__ float S_lds[TROWS][17];               // softmax output f32
    __shared__ float Sred[2][16][17];                // logits cross-wave merge
    __shared__ float cs_red[256];

    const int t = threadIdx.x;
    const int w = t >> 6;        // wave 0..3
    const int l = t & 63;
    const int l15 = l & 15;
    const int lg  = l >> 4;      // 0..3

    // stage Wt[n][k] = fp16(W[k][n])
    for (int idx = t; idx < 4096; idx += 256) {
        int k = idx >> 4, nn = idx & 15;
        Wt_u16[nn][k] = h16(W[idx]);
    }
    const float bk = b[l15];

    // P accumulators (fp16 packed, as R11)
    const int kp = t & 15;       // P phase: cluster
    const int cp = t >> 4;       // P phase: 16-wide d-chunk
    h2 Pa[8];
    #pragma unroll
    for (int j = 0; j < 8; ++j) Pa[j] = pk16(0.f, 0.f);
    float cs_acc = 0.f;

    // register prefetch: 8 float4 = this thread's slice of a tile
    float4 stg[8];
    auto load_tile = [&](int tl) {
        const float4* F4 = (const float4*)(F + (size_t)tl * TROWS * 256);
        #pragma unroll
        for (int q = 0; q < 8; ++q) {
            int r = (t >> 6) + 4 * q;
            float4 z = {0.f, 0.f, 0.f, 0.f};
            stg[q] = (tl * TROWS + r < n) ? F4[t + (q << 8)] : z;
        }
    };
    if (blockIdx.x < (unsigned)n_tiles) load_tile(blockIdx.x);
    __syncthreads();   // Wt ready

    for (int tile = blockIdx.x; tile < n_tiles; tile += gridDim.x) {
        // ---- stage row-major fp16 from registers ----
        const int c4 = t & 63;
        #pragma unroll
        for (int q = 0; q < 8; ++q) {
            int r = (t >> 6) + 4 * q;
            unsigned u0 = pk16u(stg[q].x, stg[q].y);
            unsigned u1 = pk16u(stg[q].z, stg[q].w);
            *(uint2*)&rows_u16[r][c4 << 2] = make_uint2(u0, u1);
        }
        __syncthreads();

        // prefetch next tile (overlaps MFMA + P phases)
        {
            int nt2 = tile + gridDim.x;
            if (nt2 < n_tiles) load_tile(nt2);
        }

        // ---- logits MFMA: wave w -> M-tile (w&1), K-half (w>>1) ----
        const int mt  = w & 1;
        const int ks0 = (w >> 1) * 4;
        f32x4 c0 = (f32x4){0.f, 0.f, 0.f, 0.f};
        #pragma unroll
        for (int s = 0; s < 4; ++s) {
            int k0 = (ks0 + s) << 5;
            uv4 av = *(const uv4*)&rows_u16[(mt << 4) + l15][k0 + (lg << 3)];
            uv4 bv = *(const uv4*)&Wt_u16[l15][k0 + (lg << 3)];
            c0 = __builtin_amdgcn_mfma_f32_16x16x32_f16(
                     __builtin_bit_cast(h8, av), __builtin_bit_cast(h8, bv),
                     c0, 0, 0, 0);
        }
        if (w >= 2) {
            #pragma unroll
            for (int p = 0; p < 4; ++p)
                Sred[mt][(lg << 2) + p][l15] = c0[p];
        }
        __syncthreads();

        if (w < 2) {
            // merge K-halves + bias; softmax over 16 lanes per row
            float lv[4];
            #pragma unroll
            for (int p = 0; p < 4; ++p)
                lv[p] = c0[p] + Sred[mt][(lg << 2) + p][l15] + bk;
            float mx[4], sm[4];
            #pragma unroll
            for (int p = 0; p < 4; ++p) mx[p] = lv[p];
            #pragma unroll
            for (int o = 8; o; o >>= 1)
                #pragma unroll
                for (int p = 0; p < 4; ++p)
                    mx[p] = fmaxf(mx[p], __shfl_xor(mx[p], o));
            #pragma unroll
            for (int p = 0; p < 4; ++p) { lv[p] = __expf(lv[p] - mx[p]); sm[p] = lv[p]; }
            #pragma unroll
            for (int o = 8; o; o >>= 1)
                #pragma unroll
                for (int p = 0; p < 4; ++p)
                    sm[p] += __shfl_xor(sm[p], o);
            int rbase = tile * TROWS + (mt << 4) + (lg << 2);
            #pragma unroll
            for (int p = 0; p < 4; ++p) {
                float sv = lv[p] / sm[p];
                S_lds[(mt << 4) + (lg << 2) + p][l15] = sv;
                if (rbase + p < n) cs_acc += sv;
            }
        }
        __syncthreads();   // S_lds ready

        // ---- S_out (fp32 float4) + fp8 pack from S_lds ----
        if (t < 128) {
            int r = t >> 2, c = t & 3;
            int row = tile * TROWS + r;
            if (row < n) {
                float v0 = S_lds[r][4*c + 0];
                float v1 = S_lds[r][4*c + 1];
                float v2 = S_lds[r][4*c + 2];
                float v3 = S_lds[r][4*c + 3];
                *(float4*)&S_out[((size_t)row << 4) + 4*c] = make_float4(v0, v1, v2, v3);
                unsigned u = f32_to_e4m3(v0) | (f32_to_e4m3(v1) << 8)
                           | (f32_to_e4m3(v2) << 16) | (f32_to_e4m3(v3) << 24);
                S_f8[((size_t)row << 2) + c] = u;
            }
        }

        // ---- P accumulation (R11): thread (kp,cp) owns P[kp][16cp..+15] ----
        #pragma unroll 4
        for (int r = 0; r < TROWS; ++r) {
            float sv = S_lds[r][kp];
            h2 svh = pk16(sv, sv);
            uv4 fa = *(const uv4*)&rows_u16[r][cp << 4];
            uv4 fb = *(const uv4*)&rows_u16[r][(cp << 4) + 8];
            #pragma unroll
            for (int j = 0; j < 4; ++j) {
                Pa[j]     = svh * bch2(fa[j]) + Pa[j];      // v_pk_fma_f16
                Pa[4 + j] = svh * bch2(fb[j]) + Pa[4 + j];
            }
        }
        __syncthreads();   // rows_u16/S_lds consumed
    }

    // ---- flush partials (f32) ----
    {
        float o16[16];
        #pragma unroll
        for (int j = 0; j < 8; ++j) {
            o16[2*j]     = (float)Pa[j][0];
            o16[2*j + 1] = (float)Pa[j][1];
        }
        float* dst = ws_P + (size_t)blockIdx.x * 4112 + kp * 256 + (cp << 4);
        #pragma unroll
        for (int j = 0; j < 4; ++j)
            *(float4*)&dst[4*j] = make_float4(o16[4*j], o16[4*j+1], o16[4*j+2], o16[4*j+3]);
    }
    cs_red[t] = cs_acc;
    __syncthreads();
    if (t < 16) {
        float ssum = 0.f;
        #pragma unroll
        for (int i = 0; i < 16; ++i) ssum += cs_red[t + (i << 4)];
        ws_P[(size_t)blockIdx.x * 4112 + 4096 + t] = ssum;
    }
}

__global__ void __launch_bounds__(256)
k_reduce(const float* __restrict__ ws_P, float* __restrict__ ws_red, int nb)
{
    const int seg  = blockIdx.x & (NSEG - 1);
    const int jblk = blockIdx.x / NSEG;
    const int idx  = jblk * 256 + threadIdx.x;
    if (idx >= 4112) return;
    const int chunk = (nb + NSEG - 1) / NSEG;
    const int b0 = seg * chunk;
    const int b1 = min(nb, b0 + chunk);
    float s = 0.f;
    for (int bb = b0; bb < b1; ++bb)
        s += ws_P[(size_t)bb * 4112 + idx];
    atomicAdd(&ws_red[idx], s);
}

// fused edge kernel (R11 config): 4 edges/iter, 2048 blocks
__global__ void __launch_bounds__(256, 4)
k_edge(const int* __restrict__ src0, const int* __restrict__ dst0,
       const float* __restrict__ val0, int n0,
       const int* __restrict__ src1, const int* __restrict__ dst1,
       const float* __restrict__ val1, int n1,
       const int* __restrict__ src2, const int* __restrict__ dst2,
       const float* __restrict__ val2, int n2,
       const uint4* __restrict__ S8, float* __restrict__ ws_e,
       int b0, int b1)
{
#ifndef HW_FP8
    __shared__ float lut[256];
    if (threadIdx.x < 256) {
        int i = threadIdx.x;
        int e_ = (i >> 3) & 15, m_ = i & 7, s_ = i >> 7;
        float v = e_ ? ldexpf((float)(8 + m_), e_ - 10) : ldexpf((float)m_, -9);
        lut[i] = s_ ? -v : v;
    }
    __syncthreads();
    const float* lutp = lut;
#else
    const float* lutp = nullptr;
#endif

    int g, bb, nblk, nE;
    const int* src; const int* dst; const float* val;
    if ((int)blockIdx.x < b0)      { g = 0; bb = blockIdx.x;      nblk = b0;             src = src0; dst = dst0; val = val0; nE = n0; }
    else if ((int)blockIdx.x < b1) { g = 1; bb = blockIdx.x - b0; nblk = b1 - b0;        src = src1; dst = dst1; val = val1; nE = n1; }
    else                           { g = 2; bb = blockIdx.x - b1; nblk = gridDim.x - b1; src = src2; dst = dst2; val = val2; nE = n2; }

    float m_acc = 0.f, tr_acc = 0.f;
    float gds[16];
    #pragma unroll
    for (int k = 0; k < 16; ++k) gds[k] = 0.f;

    const int nv = nE >> 2;                    // 4 edges per thread-iter
    const iv4* s4 = (const iv4*)src;
    const iv4* d4 = (const iv4*)dst;
    const fv4* v4 = (const fv4*)val;
    const int stride = nblk * 256;

    for (int i = bb * 256 + threadIdx.x; i < nv; i += stride) {
        iv4 sa = __builtin_nontemporal_load(&s4[i]);
        iv4 da = __builtin_nontemporal_load(&d4[i]);
        fv4 va = __builtin_nontemporal_load(&v4[i]);
        uint4 rs[4], rd[4];
        #pragma unroll
        for (int e = 0; e < 4; ++e) {
            rs[e] = S8[sa[e]];
            rd[e] = S8[da[e]];
        }
        #pragma unroll
        for (int e = 0; e < 4; ++e) {
            float sv[16], dv[16];
            decode16(rs[e], sv, lutp);
            decode16(rd[e], dv, lutp);
            float v = va[e];
            float dot = 0.f;
            #pragma unroll
            for (int k = 0; k < 16; ++k) dot = fmaf(sv[k], dv[k], dot);
            m_acc += v;
            tr_acc = fmaf(v, dot, tr_acc);
            #pragma unroll
            for (int k = 0; k < 16; ++k) gds[k] = fmaf(v, dv[k], gds[k]);
        }
    }

    // tail (nE % 4): block 0 of this graph
    if (bb == 0) {
        int e = (nv << 2) + threadIdx.x;
        if (e < nE) {
            float sv[16], dv[16];
            decode16(S8[src[e]], sv, lutp);
            decode16(S8[dst[e]], dv, lutp);
            float v = val[e];
            float dot = 0.f;
            #pragma unroll
            for (int k = 0; k < 16; ++k) dot = fmaf(sv[k], dv[k], dot);
            m_acc += v;
            tr_acc = fmaf(v, dot, tr_acc);
            #pragma unroll
            for (int k = 0; k < 16; ++k) gds[k] = fmaf(v, dv[k], gds[k]);
        }
    }

    #pragma unroll
    for (int o = 32; o; o >>= 1) {
        m_acc  += __shfl_xor(m_acc, o);
        tr_acc += __shfl_xor(tr_acc, o);
        #pragma unroll
        for (int k = 0; k < 16; ++k) gds[k] += __shfl_xor(gds[k], o);
    }
    __shared__ float wred[4][18];
    const int wid = threadIdx.x >> 6, lane = threadIdx.x & 63;
    if (lane == 0) {
        wred[wid][0] = m_acc; wred[wid][1] = tr_acc;
        #pragma unroll
        for (int k = 0; k < 16; ++k) wred[wid][2 + k] = gds[k];
    }
    __syncthreads();
    if (threadIdx.x < 18) {
        float s = wred[0][threadIdx.x] + wred[1][threadIdx.x]
                + wred[2][threadIdx.x] + wred[3][threadIdx.x];
        ws_e[(size_t)g * 18 * EGRID + (size_t)threadIdx.x * EGRID + bb] = s;
    }
}

__global__ void __launch_bounds__(256)
k_ereduce(const float* __restrict__ ws_e, float* __restrict__ G54,
          int g0, int g1, int g2)
{
    const int p = blockIdx.x;            // 0..53
    const int g = p / 18, slot = p % 18;
    int grids[3] = {g0, g1, g2};
    const int gb = grids[g];
    const float* base = ws_e + (size_t)g * 18 * EGRID + (size_t)slot * EGRID;

    const int t = threadIdx.x;
    float s = 0.f;
    for (int bb = t; bb < gb; bb += 256) s += base[bb];
    #pragma unroll
    for (int o = 32; o; o >>= 1) s += __shfl_xor(s, o);

    __shared__ float wr[4];
    if ((t & 63) == 0) wr[t >> 6] = s;
    __syncthreads();
    if (t == 0) G54[p] = wr[0] + wr[1] + wr[2] + wr[3];
}

__global__ void __launch_bounds__(256)
k_final(const float* __restrict__ ws_red, const float* __restrict__ G54,
        const void* __restrict__ lamda_ptr, float* __restrict__ out, int n)
{
    __shared__ float G[54];
    const int t = threadIdx.x;
    if (t < 54) G[t] = G54[t];
    __syncthreads();

    const float* P  = ws_red;
    const float* cs = ws_red + 4096;

    const float scale = 1.0507009873554805f;
    const float alpha = 1.6732632423543772f;
    for (int idx = t; idx < 4096; idx += 256) {
        int k = idx >> 8;
        float x = P[idx] / cs[k];
        float y = x > 0.f ? scale * x : scale * alpha * (expf(x) - 1.f);
        out[idx] = y;
    }

    if (t == 0) {
        int   li = *(const int*)lamda_ptr;
        float lf = *(const float*)lamda_ptr;
        float lamda = (li > -100000 && li < 100000) ? (float)li : lf;

        float m = G[0], trA = G[1];
        float ds2 = 0.f;
        for (int k = 0; k < 16; ++k) ds2 += G[2 + k] * G[2 + k];
        float spectral = -(trA - ds2 / (2.f * m)) / (2.f * m);

        float Q[2], gm[2];
        for (int g = 0; g < 2; ++g) {
            const float* Gg = G + 18 * (g + 1);
            float mg = Gg[0], trg = Gg[1];
            float gds2 = 0.f;
            for (int k = 0; k < 16; ++k) gds2 += Gg[2 + k] * Gg[2 + k];
            float safe = mg > 0.f ? mg : 1.f;
            float q = (trg - gds2 / (2.f * safe)) / (2.f * m);
            Q[g]  = mg > 0.f ? q : 0.f;
            gm[g] = mg;
        }
        float Qmin = fminf(Q[0], Q[1]);
        float gmean = 0.5f * (gm[0] + gm[1]);
        float fairness = (m / (gmean + 1e-8f)) * (-Qmin);

        float csn = 0.f;
        for (int k = 0; k < 16; ++k) csn += cs[k] * cs[k];
        float collapse = (sqrtf(csn) / (float)n) * 4.f - 1.f;

        out[4096 + (size_t)n * 16] = spectral + lamda * fairness + 0.1f * collapse;
    }
}

extern "C" void kernel_launch(void* const* d_in, const int* in_sizes, int n_in,
                              void* d_out, int out_size, void* d_ws, size_t ws_size,
                              hipStream_t stream)
{
    const float* F       = (const float*)d_in[0];
    const float* W       = (const float*)d_in[1];
    const float* b       = (const float*)d_in[2];
    const int*   adj_src = (const int*)d_in[3];
    const int*   adj_dst = (const int*)d_in[4];
    const float* adj_val = (const float*)d_in[5];
    const int*   g1_src  = (const int*)d_in[6];
    const int*   g1_dst  = (const int*)d_in[7];
    const float* g1_val  = (const float*)d_in[8];
    const int*   g2_src  = (const int*)d_in[9];
    const int*   g2_dst  = (const int*)d_in[10];
    const float* g2_val  = (const float*)d_in[11];
    const void*  lamda_p = d_in[12];

    const int n  = in_sizes[0] / 256;
    const int nE = in_sizes[3];
    const int n1 = in_sizes[6];
    const int n2 = in_sizes[9];

    float* out   = (float*)d_out;
    float* S_out = out + 4096;

    float* ws   = (float*)d_ws;
    float* ws_e = ws + OFF_E;
    float* ws_r = ws + OFF_R;
    float* ws_g = ws + OFF_G;
    unsigned* S8 = (unsigned*)(ws + OFF_F8);
    const size_t off_p = (size_t)OFF_F8 + (size_t)n * 4;
    float* ws_P = ws + off_p;

    const int n_tiles = (n + TROWS - 1) / TROWS;
    long avail = ((long)(ws_size / 4) - (long)off_p) / 4112;
    int grid1 = n_tiles < G1_MAX ? n_tiles : G1_MAX;
    if (avail < grid1) grid1 = (int)avail;
    if (grid1 < 1) grid1 = 1;

    (void)hipMemsetAsync(ws_r, 0, 4112 * sizeof(float), stream);

    k_rows<<<grid1, 256, 0, stream>>>(F, W, b, S_out, S8, ws_P, n, n_tiles);
    k_reduce<<<17 * NSEG, 256, 0, stream>>>(ws_P, ws_r, grid1);

    const int b0 = BLK0, b1g = BLK12, b2g = BLK12;
    k_edge<<<b0 + b1g + b2g, 256, 0, stream>>>(
        adj_src, adj_dst, adj_val, nE,
        g1_src, g1_dst, g1_val, n1,
        g2_src, g2_dst, g2_val, n2,
        (const uint4*)S8, ws_e, b0, b0 + b1g);

    k_ereduce<<<54, 256, 0, stream>>>(ws_e, ws_g, b0, b1g, b2g);
    k_final<<<1, 256, 0, stream>>>(ws_r, ws_g, lamda_p, out, n);
}

// Round 15
// 140.141 us; speedup vs baseline: 1.1530x; 1.0255x over previous
//
#include <hip/hip_runtime.h>
#include <cstddef>
#include <cstdint>

// ---------------------------------------------------------------------------
// MultiGroupDMoN forward.
// R15 = R14 + MFMA for the P phase too, with NO transposed staging:
//   P(16x256) += S^T(16x32) @ F(32x256); B-fragment read straight out of
//   row-major rows_u16 as a column read (8x ds_read_u16 per chunk, 4-way
//   bank conflict ~1.58x — still far cheaper than R11's 64 b128 + 256 pk_fma);
//   A-fragment from S_lds (2-way conflict = free). fp32 accumulation (MFMA C).
//   C/D write mapping identical to R13 (correctness-verified).
// k_edge: R11 config — 71us latency floor (0.29 lane-gathers/cy/CU at 96
//   outstanding; three occupancy configs all converge here).
// ws layout (floats):
//   [OFF_E .. +3*18*EGRID)   edge partials [g][slot][block]
//   [OFF_R .. +4112)         reduced P[4096]+cs[16]   (memset 0)
//   [OFF_G .. +64)           G54 reduced accumulators
//   [OFF_F8.. +4n)           fp8 S (n rows x 16 bytes, as u32)
//   [OFF_P .. +grid1*4112)   per-block k_rows partials
// ---------------------------------------------------------------------------

#define G1_MAX   1024
#define EGRID    2048
#define NSEG     16
#define OFF_E    0
#define SZ_E     (3 * 18 * EGRID)
#define OFF_R    (OFF_E + SZ_E)
#define OFF_G    (OFF_R + 4112)
#define OFF_F8   (OFF_G + 64)

#define TROWS    32
#define RSTR     264    // u16 stride: odd-dword row stride -> bank spread

#define BLK0     1024   // k_edge blocks: adj
#define BLK12    512    // k_edge blocks: g1, g2

typedef int      iv4  __attribute__((ext_vector_type(4)));
typedef float    fv4  __attribute__((ext_vector_type(4)));
typedef unsigned uv4  __attribute__((ext_vector_type(4)));
typedef _Float16 hh;
typedef hh       h2   __attribute__((ext_vector_type(2)));
typedef hh       h8   __attribute__((ext_vector_type(8)));
typedef float    f32x4 __attribute__((ext_vector_type(4)));

#if __has_builtin(__builtin_amdgcn_cvt_pk_f32_fp8)
#define HW_FP8 1
#endif

__device__ __forceinline__ h2 bch2(unsigned u) { return __builtin_bit_cast(h2, u); }

__device__ __forceinline__ unsigned pk16u(float x, float y)
{
#if __has_builtin(__builtin_amdgcn_cvt_pkrtz)
    return __builtin_bit_cast(unsigned, __builtin_amdgcn_cvt_pkrtz(x, y));
#else
    h2 r; r[0] = (hh)x; r[1] = (hh)y; return __builtin_bit_cast(unsigned, r);
#endif
}
__device__ __forceinline__ unsigned short h16(float x)
{
    return (unsigned short)(pk16u(x, 0.f) & 0xFFFFu);
}

// ---- software e4m3fn encode ----
__device__ __forceinline__ unsigned f32_to_e4m3(float f)
{
    unsigned bits = __float_as_uint(f);
    unsigned s = bits >> 31;
    int e32 = (int)((bits >> 23) & 255);
    unsigned m23 = bits & 0x7FFFFF;
    int e = e32 - 120;
    unsigned out;
    if (e32 == 0) out = 0;
    else if (e <= 0) {
        float av = fabsf(f);
        int q = (int)(av * 512.0f + 0.5f);
        out = (unsigned)q;
    } else if (e > 15) out = (15u << 3) | 6u;
    else {
        unsigned m3 = (m23 + 0x80000u) >> 20;
        if (m3 == 8u) { m3 = 0u; ++e; if (e > 15) { e = 15; m3 = 6u; } }
        out = ((unsigned)e << 3) | m3;
    }
    return out | (s << 7);
}

// ---- decode 16 fp8 bytes to floats ----
__device__ __forceinline__ void decode16(uint4 r, float* o, const float* lut)
{
#ifdef HW_FP8
    #pragma unroll
    for (int j = 0; j < 4; ++j) {
        unsigned u = (&r.x)[j];
        auto lo = __builtin_amdgcn_cvt_pk_f32_fp8(u, false);
        auto hi = __builtin_amdgcn_cvt_pk_f32_fp8(u, true);
        o[4*j]   = lo[0]; o[4*j+1] = lo[1];
        o[4*j+2] = hi[0]; o[4*j+3] = hi[1];
    }
#else
    #pragma unroll
    for (int j = 0; j < 4; ++j) {
        unsigned u = (&r.x)[j];
        #pragma unroll
        for (int q = 0; q < 4; ++q)
            o[4*j+q] = lut[(u >> (8*q)) & 255];
    }
#endif
}

__global__ void __launch_bounds__(256)
k_rows(const float* __restrict__ F, const float* __restrict__ W,
       const float* __restrict__ b, float* __restrict__ S_out,
       unsigned* __restrict__ S_f8, float* __restrict__ ws_P, int n, int n_tiles)
{
    __shared__ unsigned short Wt_u16[16][RSTR];      // Wt[n][k] fp16
    __shared__ unsigned short rows_u16[TROWS][RSTR]; // F row-major fp16
    __shared__ float S_lds[TROWS][17];               // softmax output f32
    __shared__ float Sred[2][16][17];                // logits cross-wave merge
    __shared__ float cs_red[256];

    const int t = threadIdx.x;
    const int w = t >> 6;        // wave 0..3
    const int l = t & 63;
    const int l15 = l & 15;
    const int lg  = l >> 4;      // 0..3

    // stage Wt[n][k] = fp16(W[k][n])
    for (int idx = t; idx < 4096; idx += 256) {
        int k = idx >> 4, nn = idx & 15;
        Wt_u16[nn][k] = h16(W[idx]);
    }
    const float bk = b[l15];

    // P accumulators: fp32 MFMA C, wave w owns d-chunks w*4..w*4+3
    f32x4 pacc[4];
    #pragma unroll
    for (int j = 0; j < 4; ++j) pacc[j] = (f32x4){0.f, 0.f, 0.f, 0.f};
    float cs_acc = 0.f;

    // register prefetch: 8 float4 = this thread's slice of a tile
    float4 stg[8];
    auto load_tile = [&](int tl) {
        const float4* F4 = (const float4*)(F + (size_t)tl * TROWS * 256);
        #pragma unroll
        for (int q = 0; q < 8; ++q) {
            int r = (t >> 6) + 4 * q;
            float4 z = {0.f, 0.f, 0.f, 0.f};
            stg[q] = (tl * TROWS + r < n) ? F4[t + (q << 8)] : z;
        }
    };
    if (blockIdx.x < (unsigned)n_tiles) load_tile(blockIdx.x);
    __syncthreads();   // Wt ready

    for (int tile = blockIdx.x; tile < n_tiles; tile += gridDim.x) {
        // ---- stage row-major fp16 from registers ----
        const int c4 = t & 63;
        #pragma unroll
        for (int q = 0; q < 8; ++q) {
            int r = (t >> 6) + 4 * q;
            unsigned u0 = pk16u(stg[q].x, stg[q].y);
            unsigned u1 = pk16u(stg[q].z, stg[q].w);
            *(uint2*)&rows_u16[r][c4 << 2] = make_uint2(u0, u1);
        }
        __syncthreads();

        // prefetch next tile (overlaps MFMA phases)
        {
            int nt2 = tile + gridDim.x;
            if (nt2 < n_tiles) load_tile(nt2);
        }

        // ---- logits MFMA: wave w -> M-tile (w&1), K-half (w>>1) ----
        const int mt  = w & 1;
        const int ks0 = (w >> 1) * 4;
        f32x4 c0 = (f32x4){0.f, 0.f, 0.f, 0.f};
        #pragma unroll
        for (int s = 0; s < 4; ++s) {
            int k0 = (ks0 + s) << 5;
            uv4 av = *(const uv4*)&rows_u16[(mt << 4) + l15][k0 + (lg << 3)];
            uv4 bv = *(const uv4*)&Wt_u16[l15][k0 + (lg << 3)];
            c0 = __builtin_amdgcn_mfma_f32_16x16x32_f16(
                     __builtin_bit_cast(h8, av), __builtin_bit_cast(h8, bv),
                     c0, 0, 0, 0);
        }
        if (w >= 2) {
            #pragma unroll
            for (int p = 0; p < 4; ++p)
                Sred[mt][(lg << 2) + p][l15] = c0[p];
        }
        __syncthreads();

        if (w < 2) {
            // merge K-halves + bias; softmax over 16 lanes per row
            float lv[4];
            #pragma unroll
            for (int p = 0; p < 4; ++p)
                lv[p] = c0[p] + Sred[mt][(lg << 2) + p][l15] + bk;
            float mx[4], sm[4];
            #pragma unroll
            for (int p = 0; p < 4; ++p) mx[p] = lv[p];
            #pragma unroll
            for (int o = 8; o; o >>= 1)
                #pragma unroll
                for (int p = 0; p < 4; ++p)
                    mx[p] = fmaxf(mx[p], __shfl_xor(mx[p], o));
            #pragma unroll
            for (int p = 0; p < 4; ++p) { lv[p] = __expf(lv[p] - mx[p]); sm[p] = lv[p]; }
            #pragma unroll
            for (int o = 8; o; o >>= 1)
                #pragma unroll
                for (int p = 0; p < 4; ++p)
                    sm[p] += __shfl_xor(sm[p], o);
            int rbase = tile * TROWS + (mt << 4) + (lg << 2);
            #pragma unroll
            for (int p = 0; p < 4; ++p) {
                float sv = lv[p] / sm[p];
                S_lds[(mt << 4) + (lg << 2) + p][l15] = sv;
                if (rbase + p < n) cs_acc += sv;
            }
        }
        __syncthreads();   // S_lds ready

        // ---- S_out (fp32 float4) + fp8 pack from S_lds ----
        if (t < 128) {
            int r = t >> 2, c = t & 3;
            int row = tile * TROWS + r;
            if (row < n) {
                float v0 = S_lds[r][4*c + 0];
                float v1 = S_lds[r][4*c + 1];
                float v2 = S_lds[r][4*c + 2];
                float v3 = S_lds[r][4*c + 3];
                *(float4*)&S_out[((size_t)row << 4) + 4*c] = make_float4(v0, v1, v2, v3);
                unsigned u = f32_to_e4m3(v0) | (f32_to_e4m3(v1) << 8)
                           | (f32_to_e4m3(v2) << 16) | (f32_to_e4m3(v3) << 24);
                S_f8[((size_t)row << 2) + c] = u;
            }
        }

        // ---- P MFMA: A = S^T frag from S_lds; B = column-read of rows_u16 ----
        {
            // A: lane (l15 = cluster m, lg = k-slice): S^T[l15][lg*8+j]
            float a0 = S_lds[(lg << 3) + 0][l15];
            float a1 = S_lds[(lg << 3) + 1][l15];
            float a2 = S_lds[(lg << 3) + 2][l15];
            float a3 = S_lds[(lg << 3) + 3][l15];
            float a4 = S_lds[(lg << 3) + 4][l15];
            float a5 = S_lds[(lg << 3) + 5][l15];
            float a6 = S_lds[(lg << 3) + 6][l15];
            float a7 = S_lds[(lg << 3) + 7][l15];
            uv4 au;
            au[0] = pk16u(a0, a1); au[1] = pk16u(a2, a3);
            au[2] = pk16u(a4, a5); au[3] = pk16u(a6, a7);
            h8 ah = __builtin_bit_cast(h8, au);

            #pragma unroll
            for (int j = 0; j < 4; ++j) {
                int nc = (w << 2) + j;               // d-chunk 0..15
                int dcol = (nc << 4) + l15;
                // B: F[r = lg*8 + jj][dcol], jj = 0..7 (column read)
                unsigned short b0 = rows_u16[(lg << 3) + 0][dcol];
                unsigned short b1 = rows_u16[(lg << 3) + 1][dcol];
                unsigned short b2 = rows_u16[(lg << 3) + 2][dcol];
                unsigned short b3 = rows_u16[(lg << 3) + 3][dcol];
                unsigned short b4 = rows_u16[(lg << 3) + 4][dcol];
                unsigned short b5 = rows_u16[(lg << 3) + 5][dcol];
                unsigned short b6 = rows_u16[(lg << 3) + 6][dcol];
                unsigned short b7 = rows_u16[(lg << 3) + 7][dcol];
                uv4 bu;
                bu[0] = (unsigned)b0 | ((unsigned)b1 << 16);
                bu[1] = (unsigned)b2 | ((unsigned)b3 << 16);
                bu[2] = (unsigned)b4 | ((unsigned)b5 << 16);
                bu[3] = (unsigned)b6 | ((unsigned)b7 << 16);
                pacc[j] = __builtin_amdgcn_mfma_f32_16x16x32_f16(
                              ah, __builtin_bit_cast(h8, bu), pacc[j], 0, 0, 0);
            }
        }
        __syncthreads();   // rows_u16/S_lds consumed
    }

    // ---- flush P partials (R13-verified C/D mapping):
    //      pacc[j][p] -> P[row = lg*4+p][col = w*64 + j*16 + l15]
    {
        float* dst = ws_P + (size_t)blockIdx.x * 4112;
        #pragma unroll
        for (int j = 0; j < 4; ++j)
            #pragma unroll
            for (int p = 0; p < 4; ++p)
                dst[((lg << 2) + p) * 256 + (w << 6) + (j << 4) + l15] = pacc[j][p];
    }
    cs_red[t] = cs_acc;
    __syncthreads();
    if (t < 16) {
        float ssum = 0.f;
        #pragma unroll
        for (int i = 0; i < 16; ++i) ssum += cs_red[t + (i << 4)];
        ws_P[(size_t)blockIdx.x * 4112 + 4096 + t] = ssum;
    }
}

__global__ void __launch_bounds__(256)
k_reduce(const float* __restrict__ ws_P, float* __restrict__ ws_red, int nb)
{
    const int seg  = blockIdx.x & (NSEG - 1);
    const int jblk = blockIdx.x / NSEG;
    const int idx  = jblk * 256 + threadIdx.x;
    if (idx >= 4112) return;
    const int chunk = (nb + NSEG - 1) / NSEG;
    const int b0 = seg * chunk;
    const int b1 = min(nb, b0 + chunk);
    float s = 0.f;
    for (int bb = b0; bb < b1; ++bb)
        s += ws_P[(size_t)bb * 4112 + idx];
    atomicAdd(&ws_red[idx], s);
}

// fused edge kernel (R11 config): 4 edges/iter, 2048 blocks
__global__ void __launch_bounds__(256, 4)
k_edge(const int* __restrict__ src0, const int* __restrict__ dst0,
       const float* __restrict__ val0, int n0,
       const int* __restrict__ src1, const int* __restrict__ dst1,
       const float* __restrict__ val1, int n1,
       const int* __restrict__ src2, const int* __restrict__ dst2,
       const float* __restrict__ val2, int n2,
       const uint4* __restrict__ S8, float* __restrict__ ws_e,
       int b0, int b1)
{
#ifndef HW_FP8
    __shared__ float lut[256];
    if (threadIdx.x < 256) {
        int i = threadIdx.x;
        int e_ = (i >> 3) & 15, m_ = i & 7, s_ = i >> 7;
        float v = e_ ? ldexpf((float)(8 + m_), e_ - 10) : ldexpf((float)m_, -9);
        lut[i] = s_ ? -v : v;
    }
    __syncthreads();
    const float* lutp = lut;
#else
    const float* lutp = nullptr;
#endif

    int g, bb, nblk, nE;
    const int* src; const int* dst; const float* val;
    if ((int)blockIdx.x < b0)      { g = 0; bb = blockIdx.x;      nblk = b0;             src = src0; dst = dst0; val = val0; nE = n0; }
    else if ((int)blockIdx.x < b1) { g = 1; bb = blockIdx.x - b0; nblk = b1 - b0;        src = src1; dst = dst1; val = val1; nE = n1; }
    else                           { g = 2; bb = blockIdx.x - b1; nblk = gridDim.x - b1; src = src2; dst = dst2; val = val2; nE = n2; }

    float m_acc = 0.f, tr_acc = 0.f;
    float gds[16];
    #pragma unroll
    for (int k = 0; k < 16; ++k) gds[k] = 0.f;

    const int nv = nE >> 2;                    // 4 edges per thread-iter
    const iv4* s4 = (const iv4*)src;
    const iv4* d4 = (const iv4*)dst;
    const fv4* v4 = (const fv4*)val;
    const int stride = nblk * 256;

    for (int i = bb * 256 + threadIdx.x; i < nv; i += stride) {
        iv4 sa = __builtin_nontemporal_load(&s4[i]);
        iv4 da = __builtin_nontemporal_load(&d4[i]);
        fv4 va = __builtin_nontemporal_load(&v4[i]);
        uint4 rs[4], rd[4];
        #pragma unroll
        for (int e = 0; e < 4; ++e) {
            rs[e] = S8[sa[e]];
            rd[e] = S8[da[e]];
        }
        #pragma unroll
        for (int e = 0; e < 4; ++e) {
            float sv[16], dv[16];
            decode16(rs[e], sv, lutp);
            decode16(rd[e], dv, lutp);
            float v = va[e];
            float dot = 0.f;
            #pragma unroll
            for (int k = 0; k < 16; ++k) dot = fmaf(sv[k], dv[k], dot);
            m_acc += v;
            tr_acc = fmaf(v, dot, tr_acc);
            #pragma unroll
            for (int k = 0; k < 16; ++k) gds[k] = fmaf(v, dv[k], gds[k]);
        }
    }

    // tail (nE % 4): block 0 of this graph
    if (bb == 0) {
        int e = (nv << 2) + threadIdx.x;
        if (e < nE) {
            float sv[16], dv[16];
            decode16(S8[src[e]], sv, lutp);
            decode16(S8[dst[e]], dv, lutp);
            float v = val[e];
            float dot = 0.f;
            #pragma unroll
            for (int k = 0; k < 16; ++k) dot = fmaf(sv[k], dv[k], dot);
            m_acc += v;
            tr_acc = fmaf(v, dot, tr_acc);
            #pragma unroll
            for (int k = 0; k < 16; ++k) gds[k] = fmaf(v, dv[k], gds[k]);
        }
    }

    #pragma unroll
    for (int o = 32; o; o >>= 1) {
        m_acc  += __shfl_xor(m_acc, o);
        tr_acc += __shfl_xor(tr_acc, o);
        #pragma unroll
        for (int k = 0; k < 16; ++k) gds[k] += __shfl_xor(gds[k], o);
    }
    __shared__ float wred[4][18];
    const int wid = threadIdx.x >> 6, lane = threadIdx.x & 63;
    if (lane == 0) {
        wred[wid][0] = m_acc; wred[wid][1] = tr_acc;
        #pragma unroll
        for (int k = 0; k < 16; ++k) wred[wid][2 + k] = gds[k];
    }
    __syncthreads();
    if (threadIdx.x < 18) {
        float s = wred[0][threadIdx.x] + wred[1][threadIdx.x]
                + wred[2][threadIdx.x] + wred[3][threadIdx.x];
        ws_e[(size_t)g * 18 * EGRID + (size_t)threadIdx.x * EGRID + bb] = s;
    }
}

__global__ void __launch_bounds__(256)
k_ereduce(const float* __restrict__ ws_e, float* __restrict__ G54,
          int g0, int g1, int g2)
{
    const int p = blockIdx.x;            // 0..53
    const int g = p / 18, slot = p % 18;
    int grids[3] = {g0, g1, g2};
    const int gb = grids[g];
    const float* base = ws_e + (size_t)g * 18 * EGRID + (size_t)slot * EGRID;

    const int t = threadIdx.x;
    float s = 0.f;
    for (int bb = t; bb < gb; bb += 256) s += base[bb];
    #pragma unroll
    for (int o = 32; o; o >>= 1) s += __shfl_xor(s, o);

    __shared__ float wr[4];
    if ((t & 63) == 0) wr[t >> 6] = s;
    __syncthreads();
    if (t == 0) G54[p] = wr[0] + wr[1] + wr[2] + wr[3];
}

__global__ void __launch_bounds__(256)
k_final(const float* __restrict__ ws_red, const float* __restrict__ G54,
        const void* __restrict__ lamda_ptr, float* __restrict__ out, int n)
{
    __shared__ float G[54];
    const int t = threadIdx.x;
    if (t < 54) G[t] = G54[t];
    __syncthreads();

    const float* P  = ws_red;
    const float* cs = ws_red + 4096;

    const float scale = 1.0507009873554805f;
    const float alpha = 1.6732632423543772f;
    for (int idx = t; idx < 4096; idx += 256) {
        int k = idx >> 8;
        float x = P[idx] / cs[k];
        float y = x > 0.f ? scale * x : scale * alpha * (expf(x) - 1.f);
        out[idx] = y;
    }

    if (t == 0) {
        int   li = *(const int*)lamda_ptr;
        float lf = *(const float*)lamda_ptr;
        float lamda = (li > -100000 && li < 100000) ? (float)li : lf;

        float m = G[0], trA = G[1];
        float ds2 = 0.f;
        for (int k = 0; k < 16; ++k) ds2 += G[2 + k] * G[2 + k];
        float spectral = -(trA - ds2 / (2.f * m)) / (2.f * m);

        float Q[2], gm[2];
        for (int g = 0; g < 2; ++g) {
            const float* Gg = G + 18 * (g + 1);
            float mg = Gg[0], trg = Gg[1];
            float gds2 = 0.f;
            for (int k = 0; k < 16; ++k) gds2 += Gg[2 + k] * Gg[2 + k];
            float safe = mg > 0.f ? mg : 1.f;
            float q = (trg - gds2 / (2.f * safe)) / (2.f * m);
            Q[g]  = mg > 0.f ? q : 0.f;
            gm[g] = mg;
        }
        float Qmin = fminf(Q[0], Q[1]);
        float gmean = 0.5f * (gm[0] + gm[1]);
        float fairness = (m / (gmean + 1e-8f)) * (-Qmin);

        float csn = 0.f;
        for (int k = 0; k < 16; ++k) csn += cs[k] * cs[k];
        float collapse = (sqrtf(csn) / (float)n) * 4.f - 1.f;

        out[4096 + (size_t)n * 16] = spectral + lamda * fairness + 0.1f * collapse;
    }
}

extern "C" void kernel_launch(void* const* d_in, const int* in_sizes, int n_in,
                              void* d_out, int out_size, void* d_ws, size_t ws_size,
                              hipStream_t stream)
{
    const float* F       = (const float*)d_in[0];
    const float* W       = (const float*)d_in[1];
    const float* b       = (const float*)d_in[2];
    const int*   adj_src = (const int*)d_in[3];
    const int*   adj_dst = (const int*)d_in[4];
    const float* adj_val = (const float*)d_in[5];
    const int*   g1_src  = (const int*)d_in[6];
    const int*   g1_dst  = (const int*)d_in[7];
    const float* g1_val  = (const float*)d_in[8];
    const int*   g2_src  = (const int*)d_in[9];
    const int*   g2_dst  = (const int*)d_in[10];
    const float* g2_val  = (const float*)d_in[11];
    const void*  lamda_p = d_in[12];

    const int n  = in_sizes[0] / 256;
    const int nE = in_sizes[3];
    const int n1 = in_sizes[6];
    const int n2 = in_sizes[9];

    float* out   = (float*)d_out;
    float* S_out = out + 4096;

    float* ws   = (float*)d_ws;
    float* ws_e = ws + OFF_E;
    float* ws_r = ws + OFF_R;
    float* ws_g = ws + OFF_G;
    unsigned* S8 = (unsigned*)(ws + OFF_F8);
    const size_t off_p = (size_t)OFF_F8 + (size_t)n * 4;
    float* ws_P = ws + off_p;

    const int n_tiles = (n + TROWS - 1) / TROWS;
    long avail = ((long)(ws_size / 4) - (long)off_p) / 4112;
    int grid1 = n_tiles < G1_MAX ? n_tiles : G1_MAX;
    if (avail < grid1) grid1 = (int)avail;
    if (grid1 < 1) grid1 = 1;

    (void)hipMemsetAsync(ws_r, 0, 4112 * sizeof(float), stream);

    k_rows<<<grid1, 256, 0, stream>>>(F, W, b, S_out, S8, ws_P, n, n_tiles);
    k_reduce<<<17 * NSEG, 256, 0, stream>>>(ws_P, ws_r, grid1);

    const int b0 = BLK0, b1g = BLK12, b2g = BLK12;
    k_edge<<<b0 + b1g + b2g, 256, 0, stream>>>(
        adj_src, adj_dst, adj_val, nE,
        g1_src, g1_dst, g1_val, n1,
        g2_src, g2_dst, g2_val, n2,
        (const uint4*)S8, ws_e, b0, b0 + b1g);

    k_ereduce<<<54, 256, 0, stream>>>(ws_e, ws_g, b0, b1g, b2g);
    k_final<<<1, 256, 0, stream>>>(ws_r, ws_g, lamda_p, out, n);
}